// Round 8
// baseline (199.468 us; speedup 1.0000x reference)
//
#include <hip/hip_runtime.h>
#include <hip/hip_bf16.h>

#define DEVI __device__ __forceinline__

typedef __attribute__((ext_vector_type(4))) float f32x4;
typedef __attribute__((ext_vector_type(8))) short bf16x8;

// Problem sizes
#define BB 4
#define SS 2048
#define DD 1024
#define MTOK (BB*SS)   // 8192

// Workspace layout (bytes)
#define OFF_XB  0ull
#define OFF_WB  (OFF_XB + (size_t)MTOK*DD*2)        // x bf16: 16 MB
#define OFF_Q   (OFF_WB + (size_t)3*DD*DD*2)        // W stacked bf16: 6 MB
#define OFF_K   (OFF_Q  + (size_t)MTOK*DD*2)
#define OFF_VT  (OFF_K  + (size_t)MTOK*DD*2)
#define OFF_P   (OFF_VT + (size_t)MTOK*DD*2)
#define OFF_LP  (OFF_P  + (size_t)BB*SS*SS*2)       // P bf16: 33.5 MB
#define OFF_L   (OFF_LP + (size_t)BB*16*2*SS*4)     // Lpart f32: 1 MB
#define WS_NEED (OFF_L  + (size_t)BB*SS*4)          // ~108 MB

DEVI void gload16(const __hip_bfloat16* g, __hip_bfloat16* l) {
  __builtin_amdgcn_global_load_lds(
      (const __attribute__((address_space(1))) unsigned int*)(const void*)g,
      (__attribute__((address_space(3))) unsigned int*)(void*)l, 16, 0, 0);
}

#define BAR()  __builtin_amdgcn_s_barrier()
#define LGKM() asm volatile("s_waitcnt lgkmcnt(0)" ::: "memory")
#define VM0()  asm volatile("s_waitcnt vmcnt(0)" ::: "memory")

// LDS tile layout (all cores): [rows][4 slots of 16B], row stride 64 B;
// global slot s of row r at lds slot s ^ ((r>>1)&3). Staged via pre-swizzled
// global source (global_load_lds dest linear), read with same XOR.
// Verified 0 bank conflicts (r3/r5/r6/r7).
DEVI bf16x8 fragread(const __hip_bfloat16* base, int row, int lg) {
  int slot = lg ^ ((row >> 1) & 3);
  return *reinterpret_cast<const bf16x8*>(base + row * 32 + slot * 8);
}

// =================== r6 BK=32 core (qk_scores / pv_out) =====================
DEVI void stageB3(const __hip_bfloat16* __restrict__ g, int ldg,
                  __hip_bfloat16* dst, int tid) {
  int w = tid >> 6, l = tid & 63;
  int r = l >> 2, slot = (l & 3) ^ ((l >> 3) & 3);
#pragma unroll
  for (int i = 0; i < 2; i++) {
    int c = w * 2 + i;
    gload16(g + (size_t)(c * 16 + r) * ldg + slot * 8, dst + c * 512);
  }
}

DEVI void stageA3(const __hip_bfloat16* __restrict__ g, int ldg,
                  __hip_bfloat16* dst, int tid) {
  int w = tid >> 6, l = tid & 63;
  int r = l >> 2, slot = (l & 3) ^ ((l >> 3) & 3);
#pragma unroll
  for (int i = 0; i < 4; i++) {
    int c = w * 4 + i;
    gload16(g + (size_t)(c * 16 + r) * ldg + slot * 8, dst + c * 512);
  }
}

#define BUF3 12288

DEVI void gemm_core3(const __hip_bfloat16* __restrict__ A, int lda,
                     const __hip_bfloat16* __restrict__ B, int ldb,
                     int NT, __hip_bfloat16* lds, int tid, f32x4 acc[8][4]) {
  int lane = tid & 63, lr = lane & 15, lg = lane >> 4;
  int w = tid >> 6, wm = w >> 1, wn = w & 1;

  stageA3(A, lda, lds + 0 * BUF3, tid);
  stageB3(B, ldb, lds + 0 * BUF3 + 8192, tid);
  stageA3(A + 32, lda, lds + 1 * BUF3, tid);
  stageB3(B + 32, ldb, lds + 1 * BUF3 + 8192, tid);
  asm volatile("s_waitcnt vmcnt(6)" ::: "memory");
  BAR();

  for (int t = 0; t < NT; ++t) {
    const __hip_bfloat16* cA = lds + (t % 3) * BUF3;
    const __hip_bfloat16* cB = cA + 8192;
    __hip_bfloat16* nx = lds + ((t + 2) % 3) * BUF3;
    bool st = (t + 2) < NT;

    bf16x8 af[8], bfr[4];
#pragma unroll
    for (int mi = 0; mi < 4; mi++) af[mi] = fragread(cA, wm * 128 + mi * 16 + lr, lg);
#pragma unroll
    for (int ni = 0; ni < 4; ni++) bfr[ni] = fragread(cB, wn * 64 + ni * 16 + lr, lg);
    if (st) stageA3(A + (size_t)(t + 2) * 32, lda, nx, tid);
    __builtin_amdgcn_s_setprio(1);
#pragma unroll
    for (int mi = 0; mi < 4; mi++)
#pragma unroll
      for (int ni = 0; ni < 4; ni++)
        acc[mi][ni] = __builtin_amdgcn_mfma_f32_16x16x32_bf16(af[mi], bfr[ni], acc[mi][ni], 0, 0, 0);
    __builtin_amdgcn_s_setprio(0);

#pragma unroll
    for (int mi = 4; mi < 8; mi++) af[mi] = fragread(cA, wm * 128 + mi * 16 + lr, lg);
    if (st) stageB3(B + (size_t)(t + 2) * 32, ldb, nx + 8192, tid);
    __builtin_amdgcn_s_setprio(1);
#pragma unroll
    for (int mi = 4; mi < 8; mi++)
#pragma unroll
      for (int ni = 0; ni < 4; ni++)
        acc[mi][ni] = __builtin_amdgcn_mfma_f32_16x16x32_bf16(af[mi], bfr[ni], acc[mi][ni], 0, 0, 0);
    __builtin_amdgcn_s_setprio(0);

    if (t + 2 < NT) asm volatile("s_waitcnt vmcnt(6)" ::: "memory");
    else            VM0();
    BAR();
  }
}

// ===== NEW gemm_qkv core: 256x256, BK=32, 4 buffers, counted vmcnt(8) ======
// 8 waves (2M x 4N), wave tile 128x64, acc[8][4]. LDS: 4 buffers x
// (A 256x32 16KB + B 256x32 16KB) = 128 KB. Stage tile t+3 while computing
// tile t (buf[(t+3)&3] held tile t-1: all its ds_reads retired before tile
// t-1's final barrier via MFMA dataflow). Boundary vmcnt(8): in-flight =
// tiles t+1,t+2,t+3 (12 loads/thread) -> waits tile t+1 only. Never 0
// mid-loop (T4). 2 phases/K-tile: {ds_read subtile | 2 stage loads | bar |
// lgkm | setprio 16 MFMA}; 3-K-tile staging lead (~6 phases) covers HBM.
#define TB4 16384  // elems per buffer (A 8192 + B 8192)

// Stage a 256x32 bf16 tile with 512 threads (2 loads/thread).
DEVI void stage256(const __hip_bfloat16* __restrict__ g, int ldg,
                   __hip_bfloat16* dst, int tid) {
  int w = tid >> 6, l = tid & 63;
  int r = l >> 2, slot = (l & 3) ^ ((l >> 3) & 3);
#pragma unroll
  for (int i = 0; i < 2; i++) {
    int c = w * 2 + i;  // 16-row / 1 KB chunk, wave-uniform LDS base
    gload16(g + (size_t)(c * 16 + r) * ldg + slot * 8, dst + c * 512);
  }
}

DEVI void gemm_core4(const __hip_bfloat16* __restrict__ A, int lda,
                     const __hip_bfloat16* __restrict__ B, int ldb,
                     int NT, __hip_bfloat16* lds, int tid, f32x4 acc[8][4]) {
  int lane = tid & 63, lr = lane & 15, lg = lane >> 4;
  int w = tid >> 6, wm = w >> 2, wn = w & 3;

  // prologue: stage tiles 0,1,2 (12 loads/thread); wait tile 0 (oldest 4).
#pragma unroll
  for (int p = 0; p < 3; p++) {
    stage256(A + p * 32, lda, lds + p * TB4, tid);
    stage256(B + p * 32, ldb, lds + p * TB4 + 8192, tid);
  }
  asm volatile("s_waitcnt vmcnt(8)" ::: "memory");
  BAR();

  for (int t = 0; t < NT; ++t) {
    const __hip_bfloat16* cA = lds + (t & 3) * TB4;
    const __hip_bfloat16* cB = cA + 8192;
    __hip_bfloat16* nx = lds + ((t + 3) & 3) * TB4;
    bool st = (t + 3) < NT;

    bf16x8 af[8], bfr[4];
    // ---- phase 1: af[0..3] + bf[0..3] (8 ds_read), stage A(t+3), 16 MFMA
#pragma unroll
    for (int mi = 0; mi < 4; mi++) af[mi] = fragread(cA, wm * 128 + mi * 16 + lr, lg);
#pragma unroll
    for (int ni = 0; ni < 4; ni++) bfr[ni] = fragread(cB, wn * 64 + ni * 16 + lr, lg);
    if (st) stage256(A + (size_t)(t + 3) * 32, lda, nx, tid);
    BAR(); LGKM();
    __builtin_amdgcn_s_setprio(1);
#pragma unroll
    for (int mi = 0; mi < 4; mi++)
#pragma unroll
      for (int ni = 0; ni < 4; ni++)
        acc[mi][ni] = __builtin_amdgcn_mfma_f32_16x16x32_bf16(af[mi], bfr[ni], acc[mi][ni], 0, 0, 0);
    __builtin_amdgcn_s_setprio(0);
    BAR();

    // ---- phase 2: af[4..7] (4 ds_read), stage B(t+3), 16 MFMA
#pragma unroll
    for (int mi = 4; mi < 8; mi++) af[mi] = fragread(cA, wm * 128 + mi * 16 + lr, lg);
    if (st) stage256(B + (size_t)(t + 3) * 32, ldb, nx + 8192, tid);
    BAR(); LGKM();
    __builtin_amdgcn_s_setprio(1);
#pragma unroll
    for (int mi = 4; mi < 8; mi++)
#pragma unroll
      for (int ni = 0; ni < 4; ni++)
        acc[mi][ni] = __builtin_amdgcn_mfma_f32_16x16x32_bf16(af[mi], bfr[ni], acc[mi][ni], 0, 0, 0);
    __builtin_amdgcn_s_setprio(0);

    // ---- boundary: counted wait — tile t+1 landed, t+2/t+3 stay in flight
    if (t + 3 < NT)       asm volatile("s_waitcnt vmcnt(8)" ::: "memory");
    else if (t == NT - 3) asm volatile("s_waitcnt vmcnt(4)" ::: "memory");
    else if (t == NT - 2) VM0();
    BAR();
  }
}

// ============================== cast kernels ================================
__global__ void cast_f32_bf16(const float* __restrict__ src,
                              __hip_bfloat16* __restrict__ dst, int n) {
  int i = (blockIdx.x * blockDim.x + threadIdx.x) * 4;
  if (i >= n) return;
  float4 v = *reinterpret_cast<const float4*>(src + i);
  __hip_bfloat16 h[4] = {__float2bfloat16(v.x), __float2bfloat16(v.y),
                         __float2bfloat16(v.z), __float2bfloat16(v.w)};
  *reinterpret_cast<uint2*>(dst + i) = *reinterpret_cast<const uint2*>(h);
}

__global__ void cast_w3(const float* __restrict__ Wq, const float* __restrict__ Wk,
                        const float* __restrict__ Wv, __hip_bfloat16* __restrict__ dst) {
  int i = (blockIdx.x * blockDim.x + threadIdx.x) * 4;  // over 3*DD*DD
  const int n1 = DD * DD;
  const float* src = (i < n1) ? Wq : (i < 2 * n1 ? Wk : Wv);
  int off = (i < n1) ? i : (i < 2 * n1 ? i - n1 : i - 2 * n1);
  float4 v = *reinterpret_cast<const float4*>(src + off);
  __hip_bfloat16 h[4] = {__float2bfloat16(v.x), __float2bfloat16(v.y),
                         __float2bfloat16(v.z), __float2bfloat16(v.w)};
  *reinterpret_cast<uint2*>(dst + i) = *reinterpret_cast<const uint2*>(h);
}

// ================== gemm_qkv (256x256, counted-vmcnt core) ==================
// grid: 384 blocks = mt(32) x nt(12), XCD-swizzled (384 % 8 == 0).
__launch_bounds__(512, 2)
__global__ void gemm_qkv(const __hip_bfloat16* __restrict__ xb,
                         const __hip_bfloat16* __restrict__ Wb,
                         __hip_bfloat16* __restrict__ Q,
                         __hip_bfloat16* __restrict__ Kb,
                         __hip_bfloat16* __restrict__ Vt) {
  __shared__ __hip_bfloat16 lds[4 * TB4];
  int id = blockIdx.x;
  int swz = (id & 7) * 48 + (id >> 3);
  int mt = swz / 12, nt = swz % 12;
  int tid = threadIdx.x, lane = tid & 63, lr = lane & 15, lg = lane >> 4;
  int w = tid >> 6, wm = w >> 2, wn = w & 3;
  f32x4 acc[8][4];
  f32x4 zero = {0.f, 0.f, 0.f, 0.f};
#pragma unroll
  for (int i = 0; i < 8; i++)
#pragma unroll
    for (int j = 0; j < 4; j++) acc[i][j] = zero;

  gemm_core4(xb + (size_t)mt * 256 * 1024, 1024,
             Wb + (size_t)nt * 256 * 1024, 1024, 32, lds, tid, acc);

  int which = nt >> 2;                   // 0=Q, 1=K, 2=V
  int ncol0 = (nt & 3) * 256 + wn * 64;  // col within the 1024-wide output
  int mrow0 = mt * 256 + wm * 128;
#pragma unroll
  for (int mi = 0; mi < 8; mi++)
#pragma unroll
    for (int ni = 0; ni < 4; ni++)
#pragma unroll
      for (int r = 0; r < 4; r++) {
        int row = mrow0 + mi * 16 + lg * 4 + r;
        int col = ncol0 + ni * 16 + lr;
        __hip_bfloat16 hv = __float2bfloat16(acc[mi][ni][r]);
        if (which == 0)      Q[(size_t)row * 1024 + col] = hv;
        else if (which == 1) Kb[(size_t)row * 1024 + col] = hv;
        else {
          int b = row >> 11, s = row & 2047;
          Vt[((size_t)b * 1024 + col) * 2048 + s] = hv;
        }
      }
}

// ====================== qk_scores (r6 256x128 core) =========================
__launch_bounds__(256, 2)
__global__ void qk_scores(const __hip_bfloat16* __restrict__ Q,
                          const __hip_bfloat16* __restrict__ Kb,
                          __hip_bfloat16* __restrict__ P,
                          float* __restrict__ Lpart) {
  int kt = blockIdx.x, qt = blockIdx.y, b = blockIdx.z;
  if (kt > 2 * qt + 1) return;
  __shared__ __hip_bfloat16 lds[3 * BUF3];
  int tid = threadIdx.x, lane = tid & 63, lr = lane & 15, lg = lane >> 4;
  int w = tid >> 6, wm = w >> 1, wn = w & 1;
  f32x4 acc[8][4];
  f32x4 zero = {0.f, 0.f, 0.f, 0.f};
#pragma unroll
  for (int i = 0; i < 8; i++)
#pragma unroll
    for (int j = 0; j < 4; j++) acc[i][j] = zero;

  gemm_core3(Q + ((size_t)b * 2048 + qt * 256) * 1024, 1024,
             Kb + ((size_t)b * 2048 + kt * 128) * 1024, 1024, 32, lds, tid, acc);

  const float scale = 0.03125f;  // 1/sqrt(1024)
  float part[8][4];
#pragma unroll
  for (int i = 0; i < 8; i++)
#pragma unroll
    for (int r = 0; r < 4; r++) part[i][r] = 0.f;

  __hip_bfloat16* Pb = P + (size_t)b * 2048 * 2048;
#pragma unroll
  for (int mi = 0; mi < 8; mi++)
#pragma unroll
    for (int ni = 0; ni < 4; ni++)
#pragma unroll
      for (int r = 0; r < 4; r++) {
        int q = qt * 256 + wm * 128 + mi * 16 + lg * 4 + r;
        int k = kt * 128 + wn * 64 + ni * 16 + lr;
        float p = (k <= q) ? __expf(acc[mi][ni][r] * scale) : 0.f;
        __hip_bfloat16 hv = __float2bfloat16(p);
        Pb[(size_t)q * 2048 + k] = hv;
        part[mi][r] += __bfloat162float(hv);
      }

#pragma unroll
  for (int mi = 0; mi < 8; mi++)
#pragma unroll
    for (int r = 0; r < 4; r++) {
      float s = part[mi][r];
      s += __shfl_xor(s, 1); s += __shfl_xor(s, 2);
      s += __shfl_xor(s, 4); s += __shfl_xor(s, 8);
      part[mi][r] = s;
    }
  if (lr < 4) {
#pragma unroll
    for (int mi = 0; mi < 8; mi++) {
      int q = qt * 256 + wm * 128 + mi * 16 + lg * 4 + lr;
      Lpart[(((size_t)b * 16 + kt) * 2 + wn) * 2048 + q] = part[mi][lr];
    }
  }
}

__global__ void reduce_L(const float* __restrict__ Lpart, float* __restrict__ L) {
  int i = blockIdx.x * 256 + threadIdx.x;  // [0, 8192)
  int b = i >> 11, q = i & 2047;
  int nkt = (q >> 7) + 1;
  float s = 0.f;
  for (int kt = 0; kt < nkt; kt++) {
    s += Lpart[(((size_t)b * 16 + kt) * 2 + 0) * 2048 + q];
    s += Lpart[(((size_t)b * 16 + kt) * 2 + 1) * 2048 + q];
  }
  L[i] = s;
}

// ======================== pv_out (r6 256x128 core) ==========================
__launch_bounds__(256, 2)
__global__ void pv_out(const __hip_bfloat16* __restrict__ P,
                       const __hip_bfloat16* __restrict__ Vt,
                       const float* __restrict__ L,
                       float* __restrict__ out) {
  int dt = blockIdx.x, qt = blockIdx.y, b = blockIdx.z;
  __shared__ __hip_bfloat16 lds[3 * BUF3];
  int tid = threadIdx.x, lane = tid & 63, lr = lane & 15, lg = lane >> 4;
  int w = tid >> 6, wm = w >> 1, wn = w & 1;
  f32x4 acc[8][4];
  f32x4 zero = {0.f, 0.f, 0.f, 0.f};
#pragma unroll
  for (int i = 0; i < 8; i++)
#pragma unroll
    for (int j = 0; j < 4; j++) acc[i][j] = zero;

  gemm_core3(P + (size_t)b * 2048 * 2048 + (size_t)qt * 256 * 2048, 2048,
             Vt + (size_t)b * 1024 * 2048 + (size_t)dt * 128 * 2048, 2048,
             (qt + 1) * 8, lds, tid, acc);

#pragma unroll
  for (int mi = 0; mi < 8; mi++)
#pragma unroll
    for (int r = 0; r < 4; r++) {
      int q = qt * 256 + wm * 128 + mi * 16 + lg * 4 + r;  // batch-local row
      float inv = 1.f / L[(size_t)b * 2048 + q];
#pragma unroll
      for (int ni = 0; ni < 4; ni++) {
        int d = dt * 128 + wn * 64 + ni * 16 + lr;
        out[((size_t)b * 2048 + q) * 1024 + d] = acc[mi][ni][r] * inv;
      }
    }
}

extern "C" void kernel_launch(void* const* d_in, const int* in_sizes, int n_in,
                              void* d_out, int out_size, void* d_ws, size_t ws_size,
                              hipStream_t stream) {
  const float* x  = (const float*)d_in[0];
  const float* Wq = (const float*)d_in[1];
  const float* Wk = (const float*)d_in[2];
  const float* Wv = (const float*)d_in[3];
  float* out = (float*)d_out;
  char* ws = (char*)d_ws;
  if (ws_size < WS_NEED) return;

  __hip_bfloat16* xb = (__hip_bfloat16*)(ws + OFF_XB);
  __hip_bfloat16* Wb = (__hip_bfloat16*)(ws + OFF_WB);
  __hip_bfloat16* Q  = (__hip_bfloat16*)(ws + OFF_Q);
  __hip_bfloat16* Kb = (__hip_bfloat16*)(ws + OFF_K);
  __hip_bfloat16* Vt = (__hip_bfloat16*)(ws + OFF_VT);
  __hip_bfloat16* P  = (__hip_bfloat16*)(ws + OFF_P);
  float* Lpart = (float*)(ws + OFF_LP);
  float* L     = (float*)(ws + OFF_L);

  cast_f32_bf16<<<8192, 256, 0, stream>>>(x, xb, MTOK * DD);
  cast_w3<<<3072, 256, 0, stream>>>(Wq, Wk, Wv, Wb);

  gemm_qkv<<<384, 512, 0, stream>>>(xb, Wb, Q, Kb, Vt);
  qk_scores<<<dim3(16, 8, 4), 256, 0, stream>>>(Q, Kb, P, Lpart);
  reduce_L<<<32, 256, 0, stream>>>(Lpart, L);
  pv_out<<<dim3(8, 8, 4), 256, 0, stream>>>(P, Vt, L, out);
}

// Round 9
// 197.789 us; speedup vs baseline: 1.0085x; 1.0085x over previous
//
#include <hip/hip_runtime.h>
#include <hip/hip_bf16.h>

#define DEVI __device__ __forceinline__

typedef __attribute__((ext_vector_type(4))) float f32x4;
typedef __attribute__((ext_vector_type(8))) short bf16x8;

// Problem sizes
#define BB 4
#define SS 2048
#define DD 1024
#define MTOK (BB*SS)   // 8192

// Workspace layout (bytes)
#define OFF_XB  0ull
#define OFF_WB  (OFF_XB + (size_t)MTOK*DD*2)        // x bf16: 16 MB
#define OFF_Q   (OFF_WB + (size_t)3*DD*DD*2)        // W stacked bf16: 6 MB
#define OFF_K   (OFF_Q  + (size_t)MTOK*DD*2)
#define OFF_VT  (OFF_K  + (size_t)MTOK*DD*2)
#define OFF_P   (OFF_VT + (size_t)MTOK*DD*2)
#define OFF_LP  (OFF_P  + (size_t)BB*SS*SS*2)       // P bf16: 33.5 MB
#define OFF_L   (OFF_LP + (size_t)BB*16*2*SS*4)     // Lpart f32: 1 MB
#define WS_NEED (OFF_L  + (size_t)BB*SS*4)          // ~108 MB

DEVI void gload16(const __hip_bfloat16* g, __hip_bfloat16* l) {
  __builtin_amdgcn_global_load_lds(
      (const __attribute__((address_space(1))) unsigned int*)(const void*)g,
      (__attribute__((address_space(3))) unsigned int*)(void*)l, 16, 0, 0);
}

#define BAR()  __builtin_amdgcn_s_barrier()

// LDS tile layout: [rows][4 slots of 16B], row stride 64 B; global slot s of
// row r at lds slot s ^ ((r>>1)&3). Staged via pre-swizzled global source
// (global_load_lds dest linear), read with same XOR. 0 conflicts (r3-r8).
DEVI bf16x8 fragread(const __hip_bfloat16* base, int row, int lg) {
  int slot = lg ^ ((row >> 1) & 3);
  return *reinterpret_cast<const bf16x8*>(base + row * 32 + slot * 8);
}

// Stage a 128x32 bf16 tile (2 loads/thread, 256 threads / 4 waves).
DEVI void stageB3(const __hip_bfloat16* __restrict__ g, int ldg,
                  __hip_bfloat16* dst, int tid) {
  int w = tid >> 6, l = tid & 63;
  int r = l >> 2, slot = (l & 3) ^ ((l >> 3) & 3);
#pragma unroll
  for (int i = 0; i < 2; i++) {
    int c = w * 2 + i;
    gload16(g + (size_t)(c * 16 + r) * ldg + slot * 8, dst + c * 512);
  }
}

// Stage a 256x32 bf16 tile (4 loads/thread, 256 threads / 4 waves).
DEVI void stageA3(const __hip_bfloat16* __restrict__ g, int ldg,
                  __hip_bfloat16* dst, int tid) {
  int w = tid >> 6, l = tid & 63;
  int r = l >> 2, slot = (l & 3) ^ ((l >> 3) & 3);
#pragma unroll
  for (int i = 0; i < 4; i++) {
    int c = w * 4 + i;
    gload16(g + (size_t)(c * 16 + r) * ldg + slot * 8, dst + c * 512);
  }
}

#define BUF3 12288

DEVI void mfma16(const bf16x8 a[4], const bf16x8 b[4], f32x4 acc[8][4], int mo) {
  __builtin_amdgcn_s_setprio(1);
#pragma unroll
  for (int m = 0; m < 4; m++)
#pragma unroll
    for (int n = 0; n < 4; n++)
      acc[mo + m][n] = __builtin_amdgcn_mfma_f32_16x16x32_bf16(a[m], b[n], acc[mo + m][n], 0, 0, 0);
  __builtin_amdgcn_s_setprio(0);
}

// ========== pipelined 256x128 core (4 waves, acc[8][4] per wave) ============
// Register-level fragment pipeline: entering iter t, af01(t) and BC(t) are
// already in registers (read during iter t-1's h1). Per iter:
//   h0: read af45(t) | stage A(t+2) | MFMA(af01 x BC)   <- inputs ~1 phase old
//   mid: stage B(t+2) | counted vmcnt(6) | barrier      <- t+1 landed
//   h1: read af01(t+1)+BN(t+1) | MFMA(af45 x BC)        <- af45 covered by h0
//   barrier                                             <- buf-reuse safety
// No manual lgkmcnt: compiler dataflow inserts fine-grained waits (m97).
// vmcnt math: before the wait, in flight = t+1's 6 + A(t+2) 4 + B(t+2) 2 = 12
// -> vmcnt(6) drains exactly tile t+1 (issued one iter earlier, ~free).
// B-frags double-buffered (BC/BN) with static parity unroll (rule #20).
DEVI void iter_step(const __hip_bfloat16* __restrict__ A, int lda,
                    const __hip_bfloat16* __restrict__ B, int ldb,
                    int t, int NT, __hip_bfloat16* lds, int tid,
                    int wm, int wn, int lr, int lg,
                    bf16x8 af01[4], bf16x8 af45[4],
                    bf16x8 BC[4], bf16x8 BN[4], f32x4 acc[8][4]) {
  const __hip_bfloat16* cA = lds + (t % 3) * BUF3;
  __hip_bfloat16* nx = lds + ((t + 2) % 3) * BUF3;
  bool st = (t + 2) < NT;

  // ---- h0 ----
#pragma unroll
  for (int m = 0; m < 4; m++) af45[m] = fragread(cA, wm * 128 + (4 + m) * 16 + lr, lg);
  if (st) stageA3(A + (size_t)(t + 2) * 32, lda, nx, tid);
  mfma16(af01, BC, acc, 0);

  // ---- mid ----
  if (st) {
    stageB3(B + (size_t)(t + 2) * 32, ldb, nx + 8192, tid);
    asm volatile("s_waitcnt vmcnt(6)" ::: "memory");
  } else {
    asm volatile("s_waitcnt vmcnt(0)" ::: "memory");
  }
  BAR();

  // ---- h1 ----
  if (t + 1 < NT) {
    const __hip_bfloat16* nA = lds + ((t + 1) % 3) * BUF3;
#pragma unroll
    for (int m = 0; m < 4; m++) af01[m] = fragread(nA, wm * 128 + m * 16 + lr, lg);
#pragma unroll
    for (int n = 0; n < 4; n++) BN[n] = fragread(nA + 8192, wn * 64 + n * 16 + lr, lg);
  }
  mfma16(af45, BC, acc, 4);
  BAR();
}

// NT must be even and >= 2 (all call sites: 32 or (qt+1)*8).
DEVI void gemm_core3p(const __hip_bfloat16* __restrict__ A, int lda,
                      const __hip_bfloat16* __restrict__ B, int ldb,
                      int NT, __hip_bfloat16* lds, int tid, f32x4 acc[8][4]) {
  int lane = tid & 63, lr = lane & 15, lg = lane >> 4;
  int w = tid >> 6, wm = w >> 1, wn = w & 1;

  // prologue: stage tiles 0,1; wait tile 0; preload frags of tile 0.
  stageA3(A, lda, lds + 0 * BUF3, tid);
  stageB3(B, ldb, lds + 0 * BUF3 + 8192, tid);
  stageA3(A + 32, lda, lds + 1 * BUF3, tid);
  stageB3(B + 32, ldb, lds + 1 * BUF3 + 8192, tid);
  asm volatile("s_waitcnt vmcnt(6)" ::: "memory");
  BAR();

  bf16x8 af01[4], af45[4], bfrA[4], bfrB[4];
#pragma unroll
  for (int m = 0; m < 4; m++) af01[m] = fragread(lds, wm * 128 + m * 16 + lr, lg);
#pragma unroll
  for (int n = 0; n < 4; n++) bfrA[n] = fragread(lds + 8192, wn * 64 + n * 16 + lr, lg);

  for (int t = 0; t < NT; t += 2) {
    iter_step(A, lda, B, ldb, t,     NT, lds, tid, wm, wn, lr, lg, af01, af45, bfrA, bfrB, acc);
    iter_step(A, lda, B, ldb, t + 1, NT, lds, tid, wm, wn, lr, lg, af01, af45, bfrB, bfrA, acc);
  }
}

// ============================== cast kernels ================================
__global__ void cast_f32_bf16(const float* __restrict__ src,
                              __hip_bfloat16* __restrict__ dst, int n) {
  int i = (blockIdx.x * blockDim.x + threadIdx.x) * 4;
  if (i >= n) return;
  float4 v = *reinterpret_cast<const float4*>(src + i);
  __hip_bfloat16 h[4] = {__float2bfloat16(v.x), __float2bfloat16(v.y),
                         __float2bfloat16(v.z), __float2bfloat16(v.w)};
  *reinterpret_cast<uint2*>(dst + i) = *reinterpret_cast<const uint2*>(h);
}

__global__ void cast_w3(const float* __restrict__ Wq, const float* __restrict__ Wk,
                        const float* __restrict__ Wv, __hip_bfloat16* __restrict__ dst) {
  int i = (blockIdx.x * blockDim.x + threadIdx.x) * 4;  // over 3*DD*DD
  const int n1 = DD * DD;
  const float* src = (i < n1) ? Wq : (i < 2 * n1 ? Wk : Wv);
  int off = (i < n1) ? i : (i < 2 * n1 ? i - n1 : i - 2 * n1);
  float4 v = *reinterpret_cast<const float4*>(src + off);
  __hip_bfloat16 h[4] = {__float2bfloat16(v.x), __float2bfloat16(v.y),
                         __float2bfloat16(v.z), __float2bfloat16(v.w)};
  *reinterpret_cast<uint2*>(dst + i) = *reinterpret_cast<const uint2*>(h);
}

// ===================== gemm_qkv (256x128, pipelined core) ===================
// grid: 768 blocks (mt 32 x nt 24), 1D XCD-swizzled (768 % 8 == 0).
__launch_bounds__(256, 2)
__global__ void gemm_qkv(const __hip_bfloat16* __restrict__ xb,
                         const __hip_bfloat16* __restrict__ Wb,
                         __hip_bfloat16* __restrict__ Q,
                         __hip_bfloat16* __restrict__ Kb,
                         __hip_bfloat16* __restrict__ Vt) {
  __shared__ __hip_bfloat16 lds[3 * BUF3];
  int id = blockIdx.x;
  int swz = (id & 7) * 96 + (id >> 3);
  int mt = swz / 24, nt = swz % 24;
  int tid = threadIdx.x, lane = tid & 63, lr = lane & 15, lg = lane >> 4;
  int w = tid >> 6, wm = w >> 1, wn = w & 1;
  f32x4 acc[8][4];
  f32x4 zero = {0.f, 0.f, 0.f, 0.f};
#pragma unroll
  for (int i = 0; i < 8; i++)
#pragma unroll
    for (int j = 0; j < 4; j++) acc[i][j] = zero;

  gemm_core3p(xb + (size_t)mt * 256 * 1024, 1024,
              Wb + (size_t)nt * 128 * 1024, 1024, 32, lds, tid, acc);

  int which = nt >> 3;                  // 0=Q, 1=K, 2=V
  int ncol0 = (nt & 7) * 128 + wn * 64;
  int mrow0 = mt * 256 + wm * 128;
#pragma unroll
  for (int mi = 0; mi < 8; mi++)
#pragma unroll
    for (int ni = 0; ni < 4; ni++)
#pragma unroll
      for (int r = 0; r < 4; r++) {
        int row = mrow0 + mi * 16 + lg * 4 + r;
        int col = ncol0 + ni * 16 + lr;
        __hip_bfloat16 hv = __float2bfloat16(acc[mi][ni][r]);
        if (which == 0)      Q[(size_t)row * 1024 + col] = hv;
        else if (which == 1) Kb[(size_t)row * 1024 + col] = hv;
        else {
          int b = row >> 11, s = row & 2047;
          Vt[((size_t)b * 1024 + col) * 2048 + s] = hv;
        }
      }
}

// ==================== qk_scores (256x128, pipelined core) ===================
__launch_bounds__(256, 2)
__global__ void qk_scores(const __hip_bfloat16* __restrict__ Q,
                          const __hip_bfloat16* __restrict__ Kb,
                          __hip_bfloat16* __restrict__ P,
                          float* __restrict__ Lpart) {
  int kt = blockIdx.x, qt = blockIdx.y, b = blockIdx.z;
  if (kt > 2 * qt + 1) return;
  __shared__ __hip_bfloat16 lds[3 * BUF3];
  int tid = threadIdx.x, lane = tid & 63, lr = lane & 15, lg = lane >> 4;
  int w = tid >> 6, wm = w >> 1, wn = w & 1;
  f32x4 acc[8][4];
  f32x4 zero = {0.f, 0.f, 0.f, 0.f};
#pragma unroll
  for (int i = 0; i < 8; i++)
#pragma unroll
    for (int j = 0; j < 4; j++) acc[i][j] = zero;

  gemm_core3p(Q + ((size_t)b * 2048 + qt * 256) * 1024, 1024,
              Kb + ((size_t)b * 2048 + kt * 128) * 1024, 1024, 32, lds, tid, acc);

  const float scale = 0.03125f;  // 1/sqrt(1024)
  float part[8][4];
#pragma unroll
  for (int i = 0; i < 8; i++)
#pragma unroll
    for (int r = 0; r < 4; r++) part[i][r] = 0.f;

  __hip_bfloat16* Pb = P + (size_t)b * 2048 * 2048;
#pragma unroll
  for (int mi = 0; mi < 8; mi++)
#pragma unroll
    for (int ni = 0; ni < 4; ni++)
#pragma unroll
      for (int r = 0; r < 4; r++) {
        int q = qt * 256 + wm * 128 + mi * 16 + lg * 4 + r;
        int k = kt * 128 + wn * 64 + ni * 16 + lr;
        float p = (k <= q) ? __expf(acc[mi][ni][r] * scale) : 0.f;
        __hip_bfloat16 hv = __float2bfloat16(p);
        Pb[(size_t)q * 2048 + k] = hv;
        part[mi][r] += __bfloat162float(hv);
      }

#pragma unroll
  for (int mi = 0; mi < 8; mi++)
#pragma unroll
    for (int r = 0; r < 4; r++) {
      float s = part[mi][r];
      s += __shfl_xor(s, 1); s += __shfl_xor(s, 2);
      s += __shfl_xor(s, 4); s += __shfl_xor(s, 8);
      part[mi][r] = s;
    }
  if (lr < 4) {
#pragma unroll
    for (int mi = 0; mi < 8; mi++) {
      int q = qt * 256 + wm * 128 + mi * 16 + lg * 4 + lr;
      Lpart[(((size_t)b * 16 + kt) * 2 + wn) * 2048 + q] = part[mi][lr];
    }
  }
}

__global__ void reduce_L(const float* __restrict__ Lpart, float* __restrict__ L) {
  int i = blockIdx.x * 256 + threadIdx.x;  // [0, 8192)
  int b = i >> 11, q = i & 2047;
  int nkt = (q >> 7) + 1;
  float s = 0.f;
  for (int kt = 0; kt < nkt; kt++) {
    s += Lpart[(((size_t)b * 16 + kt) * 2 + 0) * 2048 + q];
    s += Lpart[(((size_t)b * 16 + kt) * 2 + 1) * 2048 + q];
  }
  L[i] = s;
}

// ===================== pv_out (256x128, pipelined core) =====================
__launch_bounds__(256, 2)
__global__ void pv_out(const __hip_bfloat16* __restrict__ P,
                       const __hip_bfloat16* __restrict__ Vt,
                       const float* __restrict__ L,
                       float* __restrict__ out) {
  int dt = blockIdx.x, qt = blockIdx.y, b = blockIdx.z;
  __shared__ __hip_bfloat16 lds[3 * BUF3];
  int tid = threadIdx.x, lane = tid & 63, lr = lane & 15, lg = lane >> 4;
  int w = tid >> 6, wm = w >> 1, wn = w & 1;
  f32x4 acc[8][4];
  f32x4 zero = {0.f, 0.f, 0.f, 0.f};
#pragma unroll
  for (int i = 0; i < 8; i++)
#pragma unroll
    for (int j = 0; j < 4; j++) acc[i][j] = zero;

  gemm_core3p(P + (size_t)b * 2048 * 2048 + (size_t)qt * 256 * 2048, 2048,
              Vt + (size_t)b * 1024 * 2048 + (size_t)dt * 128 * 2048, 2048,
              (qt + 1) * 8, lds, tid, acc);

#pragma unroll
  for (int mi = 0; mi < 8; mi++)
#pragma unroll
    for (int r = 0; r < 4; r++) {
      int q = qt * 256 + wm * 128 + mi * 16 + lg * 4 + r;  // batch-local row
      float inv = 1.f / L[(size_t)b * 2048 + q];
#pragma unroll
      for (int ni = 0; ni < 4; ni++) {
        int d = dt * 128 + wn * 64 + ni * 16 + lr;
        out[((size_t)b * 2048 + q) * 1024 + d] = acc[mi][ni][r] * inv;
      }
    }
}

extern "C" void kernel_launch(void* const* d_in, const int* in_sizes, int n_in,
                              void* d_out, int out_size, void* d_ws, size_t ws_size,
                              hipStream_t stream) {
  const float* x  = (const float*)d_in[0];
  const float* Wq = (const float*)d_in[1];
  const float* Wk = (const float*)d_in[2];
  const float* Wv = (const float*)d_in[3];
  float* out = (float*)d_out;
  char* ws = (char*)d_ws;
  if (ws_size < WS_NEED) return;

  __hip_bfloat16* xb = (__hip_bfloat16*)(ws + OFF_XB);
  __hip_bfloat16* Wb = (__hip_bfloat16*)(ws + OFF_WB);
  __hip_bfloat16* Q  = (__hip_bfloat16*)(ws + OFF_Q);
  __hip_bfloat16* Kb = (__hip_bfloat16*)(ws + OFF_K);
  __hip_bfloat16* Vt = (__hip_bfloat16*)(ws + OFF_VT);
  __hip_bfloat16* P  = (__hip_bfloat16*)(ws + OFF_P);
  float* Lpart = (float*)(ws + OFF_LP);
  float* L     = (float*)(ws + OFF_L);

  cast_f32_bf16<<<8192, 256, 0, stream>>>(x, xb, MTOK * DD);
  cast_w3<<<3072, 256, 0, stream>>>(Wq, Wk, Wv, Wb);

  gemm_qkv<<<768, 256, 0, stream>>>(xb, Wb, Q, Kb, Vt);
  qk_scores<<<dim3(16, 8, 4), 256, 0, stream>>>(Q, Kb, P, Lpart);
  reduce_L<<<32, 256, 0, stream>>>(Lpart, L);
  pv_out<<<dim3(8, 8, 4), 256, 0, stream>>>(P, Vt, L, out);
}

// Round 10
// 197.026 us; speedup vs baseline: 1.0124x; 1.0039x over previous
//
#include <hip/hip_runtime.h>
#include <hip/hip_bf16.h>

#define DEVI __device__ __forceinline__

typedef __attribute__((ext_vector_type(4))) float f32x4;
typedef __attribute__((ext_vector_type(8))) short bf16x8;

// Problem sizes
#define BB 4
#define SS 2048
#define DD 1024
#define MTOK (BB*SS)   // 8192

// Workspace layout (bytes)
#define OFF_XB  0ull
#define OFF_WB  (OFF_XB + (size_t)MTOK*DD*2)        // x bf16: 16 MB
#define OFF_Q   (OFF_WB + (size_t)3*DD*DD*2)        // W stacked bf16: 6 MB
#define OFF_K   (OFF_Q  + (size_t)MTOK*DD*2)
#define OFF_VT  (OFF_K  + (size_t)MTOK*DD*2)
#define OFF_P   (OFF_VT + (size_t)MTOK*DD*2)
#define OFF_LP  (OFF_P  + (size_t)BB*SS*SS*2)       // P bf16: 33.5 MB
#define OFF_L   (OFF_LP + (size_t)BB*16*2*SS*4)     // Lpart f32: 1 MB
#define WS_NEED (OFF_L  + (size_t)BB*SS*4)          // ~108 MB

DEVI void gload16(const __hip_bfloat16* g, __hip_bfloat16* l) {
  __builtin_amdgcn_global_load_lds(
      (const __attribute__((address_space(1))) unsigned int*)(const void*)g,
      (__attribute__((address_space(3))) unsigned int*)(void*)l, 16, 0, 0);
}

#define BAR()  __builtin_amdgcn_s_barrier()
#define LGKM() asm volatile("s_waitcnt lgkmcnt(0)" ::: "memory")
#define VMC(n) asm volatile("s_waitcnt vmcnt(" #n ")" ::: "memory")

// LDS region layout (all cores): [rows][4 slots of 16B], row stride 64 B;
// global slot s of row r at lds slot s ^ ((r>>1)&3). Staged via pre-swizzled
// global source (global_load_lds dest linear), read with same XOR.
// Verified 0 bank conflicts (r3-r9).
DEVI bf16x8 fragread(const __hip_bfloat16* base, int row, int lg) {
  int slot = lg ^ ((row >> 1) & 3);
  return *reinterpret_cast<const bf16x8*>(base + row * 32 + slot * 8);
}

DEVI void mfma16(const bf16x8 a[4], const bf16x8 b[4], f32x4 acc[8][4], int mo) {
  __builtin_amdgcn_s_setprio(1);
#pragma unroll
  for (int m = 0; m < 4; m++)
#pragma unroll
    for (int n = 0; n < 4; n++)
      acc[mo + m][n] = __builtin_amdgcn_mfma_f32_16x16x32_bf16(a[m], b[n], acc[mo + m][n], 0, 0, 0);
  __builtin_amdgcn_s_setprio(0);
}

// =================== r9 pipelined core (qk_scores / pv_out) =================
DEVI void stageB3(const __hip_bfloat16* __restrict__ g, int ldg,
                  __hip_bfloat16* dst, int tid) {
  int w = tid >> 6, l = tid & 63;
  int r = l >> 2, slot = (l & 3) ^ ((l >> 3) & 3);
#pragma unroll
  for (int i = 0; i < 2; i++) {
    int c = w * 2 + i;
    gload16(g + (size_t)(c * 16 + r) * ldg + slot * 8, dst + c * 512);
  }
}

DEVI void stageA3(const __hip_bfloat16* __restrict__ g, int ldg,
                  __hip_bfloat16* dst, int tid) {
  int w = tid >> 6, l = tid & 63;
  int r = l >> 2, slot = (l & 3) ^ ((l >> 3) & 3);
#pragma unroll
  for (int i = 0; i < 4; i++) {
    int c = w * 4 + i;
    gload16(g + (size_t)(c * 16 + r) * ldg + slot * 8, dst + c * 512);
  }
}

#define BUF3 12288

DEVI void iter_step(const __hip_bfloat16* __restrict__ A, int lda,
                    const __hip_bfloat16* __restrict__ B, int ldb,
                    int t, int NT, __hip_bfloat16* lds, int tid,
                    int wm, int wn, int lr, int lg,
                    bf16x8 af01[4], bf16x8 af45[4],
                    bf16x8 BC[4], bf16x8 BN[4], f32x4 acc[8][4]) {
  const __hip_bfloat16* cA = lds + (t % 3) * BUF3;
  __hip_bfloat16* nx = lds + ((t + 2) % 3) * BUF3;
  bool st = (t + 2) < NT;

#pragma unroll
  for (int m = 0; m < 4; m++) af45[m] = fragread(cA, wm * 128 + (4 + m) * 16 + lr, lg);
  if (st) stageA3(A + (size_t)(t + 2) * 32, lda, nx, tid);
  mfma16(af01, BC, acc, 0);

  if (st) {
    stageB3(B + (size_t)(t + 2) * 32, ldb, nx + 8192, tid);
    VMC(6);
  } else {
    VMC(0);
  }
  BAR();

  if (t + 1 < NT) {
    const __hip_bfloat16* nA = lds + ((t + 1) % 3) * BUF3;
#pragma unroll
    for (int m = 0; m < 4; m++) af01[m] = fragread(nA, wm * 128 + m * 16 + lr, lg);
#pragma unroll
    for (int n = 0; n < 4; n++) BN[n] = fragread(nA + 8192, wn * 64 + n * 16 + lr, lg);
  }
  mfma16(af45, BC, acc, 4);
  BAR();
}

DEVI void gemm_core3p(const __hip_bfloat16* __restrict__ A, int lda,
                      const __hip_bfloat16* __restrict__ B, int ldb,
                      int NT, __hip_bfloat16* lds, int tid, f32x4 acc[8][4]) {
  int lane = tid & 63, lr = lane & 15, lg = lane >> 4;
  int w = tid >> 6, wm = w >> 1, wn = w & 1;

  stageA3(A, lda, lds + 0 * BUF3, tid);
  stageB3(B, ldb, lds + 0 * BUF3 + 8192, tid);
  stageA3(A + 32, lda, lds + 1 * BUF3, tid);
  stageB3(B + 32, ldb, lds + 1 * BUF3 + 8192, tid);
  VMC(6);
  BAR();

  bf16x8 af01[4], af45[4], bfrA[4], bfrB[4];
#pragma unroll
  for (int m = 0; m < 4; m++) af01[m] = fragread(lds, wm * 128 + m * 16 + lr, lg);
#pragma unroll
  for (int n = 0; n < 4; n++) bfrA[n] = fragread(lds + 8192, wn * 64 + n * 16 + lr, lg);

  for (int t = 0; t < NT; t += 2) {
    iter_step(A, lda, B, ldb, t,     NT, lds, tid, wm, wn, lr, lg, af01, af45, bfrA, bfrB, acc);
    iter_step(A, lda, B, ldb, t + 1, NT, lds, tid, wm, wn, lr, lg, af01, af45, bfrB, bfrA, acc);
  }
}

// ======= NEW: faithful m201 8-phase 256x256 core, BK=64 (gemm_qkv) ==========
// 8 waves (wm=w>>2 in {0,1}: 128 rows; wn=w&3: 64 cols), acc[8][4].
// LDS: 2 buffers x 4 regions (Akh0,Akh1,Bkh0,Bkh1; each a 256x32 zero-conflict
// tile, 16 KB) = 128 KB. Staging: one region per phase, in consumption order
// (P1->Y.Akh0, P2->Y.Bkh0, P3->Y.Akh1, P4->Y.Bkh1), giving every region 3-4
// phases of flight before its counted wait. Counted vmcnt(4) ONLY before the
// P2-close and P4-close barriers: retires exactly the 4 oldest loads (the
// regions the next 2 phases read), always leaves 4 in flight (T4: never 0
// mid-loop). wait-then-barrier => cross-wave visibility of staged chunks.
// Buffer-overwrite safety: region R of buf Y staged at tile t was last read
// at tile t-1 (phase <= P4), whose reads retired before that phase's MFMA
// (compiler dataflow lgkm) and thus before its closing barrier.
#define REG8 8192   // elems per 256x32 region
#define BUFE (4*REG8)

// Stage a 256x32 region (2 loads/thread, 512 threads), pre-swizzled source.
DEVI void stage256(const __hip_bfloat16* __restrict__ g, int ldg,
                   __hip_bfloat16* dst, int tid) {
  int w = tid >> 6, l = tid & 63;
  int r = l >> 2, slot = (l & 3) ^ ((l >> 3) & 3);
#pragma unroll
  for (int i = 0; i < 2; i++) {
    int c = w * 2 + i;  // 16-row / 1 KB chunk, wave-uniform LDS base
    gload16(g + (size_t)(c * 16 + r) * ldg + slot * 8, dst + c * 512);
  }
}

DEVI void gemm8ph(const __hip_bfloat16* __restrict__ A, int lda,
                  const __hip_bfloat16* __restrict__ B, int ldb,
                  int NT, __hip_bfloat16* lds, int tid, f32x4 acc[8][4]) {
  int lane = tid & 63, lr = lane & 15, lg = lane >> 4;
  int w = tid >> 6, wm = w >> 2, wn = w & 3;

  // prologue: tile 0 into buf0, consumption order; wait first 2 regions.
  stage256(A,      lda, lds + 0 * REG8, tid);  // Akh0
  stage256(B,      ldb, lds + 2 * REG8, tid);  // Bkh0
  stage256(A + 32, lda, lds + 1 * REG8, tid);  // Akh1
  stage256(B + 32, ldb, lds + 3 * REG8, tid);  // Bkh1
  VMC(4);
  BAR();

  bf16x8 af[4], bq[4];
  for (int t = 0; t < NT; ++t) {
    const __hip_bfloat16* X = lds + (size_t)(t & 1) * BUFE;
    __hip_bfloat16* Y = lds + (size_t)((t + 1) & 1) * BUFE;
    bool st = (t + 1) < NT;
    const __hip_bfloat16* An = A + (size_t)(t + 1) * 64;
    const __hip_bfloat16* Bn = B + (size_t)(t + 1) * 64;

    // ---- P1: A-kh0 lo + B-kh0 (8 reads) | stage Y.Akh0 | 16 MFMA ----
#pragma unroll
    for (int m = 0; m < 4; m++) af[m] = fragread(X, wm * 128 + m * 16 + lr, lg);
#pragma unroll
    for (int n = 0; n < 4; n++) bq[n] = fragread(X + 2 * REG8, wn * 64 + n * 16 + lr, lg);
    if (st) stage256(An, lda, Y, tid);
    BAR(); LGKM();
    mfma16(af, bq, acc, 0);
    BAR();

    // ---- P2: A-kh0 hi (4 reads) | stage Y.Bkh0 | 16 MFMA | vmcnt ----
#pragma unroll
    for (int m = 0; m < 4; m++) af[m] = fragread(X, wm * 128 + (4 + m) * 16 + lr, lg);
    if (st) stage256(Bn, ldb, Y + 2 * REG8, tid);
    BAR(); LGKM();
    mfma16(af, bq, acc, 4);
    if (st) VMC(4); else VMC(0);   // retire X.Akh1, X.Bkh1 (read next phases)
    BAR();

    // ---- P3: A-kh1 lo + B-kh1 (8 reads) | stage Y.Akh1 | 16 MFMA ----
#pragma unroll
    for (int m = 0; m < 4; m++) af[m] = fragread(X + REG8, wm * 128 + m * 16 + lr, lg);
#pragma unroll
    for (int n = 0; n < 4; n++) bq[n] = fragread(X + 3 * REG8, wn * 64 + n * 16 + lr, lg);
    if (st) stage256(An + 32, lda, Y + REG8, tid);
    BAR(); LGKM();
    mfma16(af, bq, acc, 0);
    BAR();

    // ---- P4: A-kh1 hi (4 reads) | stage Y.Bkh1 | 16 MFMA | vmcnt ----
#pragma unroll
    for (int m = 0; m < 4; m++) af[m] = fragread(X + REG8, wm * 128 + (4 + m) * 16 + lr, lg);
    if (st) stage256(Bn + 32, ldb, Y + 3 * REG8, tid);
    BAR(); LGKM();
    mfma16(af, bq, acc, 4);
    if (st) VMC(4);                // retire Y.Akh0, Y.Bkh0 (next tile's P1/P2)
    BAR();
  }
}

// ============================== cast kernels ================================
__global__ void cast_f32_bf16(const float* __restrict__ src,
                              __hip_bfloat16* __restrict__ dst, int n) {
  int i = (blockIdx.x * blockDim.x + threadIdx.x) * 4;
  if (i >= n) return;
  float4 v = *reinterpret_cast<const float4*>(src + i);
  __hip_bfloat16 h[4] = {__float2bfloat16(v.x), __float2bfloat16(v.y),
                         __float2bfloat16(v.z), __float2bfloat16(v.w)};
  *reinterpret_cast<uint2*>(dst + i) = *reinterpret_cast<const uint2*>(h);
}

__global__ void cast_w3(const float* __restrict__ Wq, const float* __restrict__ Wk,
                        const float* __restrict__ Wv, __hip_bfloat16* __restrict__ dst) {
  int i = (blockIdx.x * blockDim.x + threadIdx.x) * 4;  // over 3*DD*DD
  const int n1 = DD * DD;
  const float* src = (i < n1) ? Wq : (i < 2 * n1 ? Wk : Wv);
  int off = (i < n1) ? i : (i < 2 * n1 ? i - n1 : i - 2 * n1);
  float4 v = *reinterpret_cast<const float4*>(src + off);
  __hip_bfloat16 h[4] = {__float2bfloat16(v.x), __float2bfloat16(v.y),
                         __float2bfloat16(v.z), __float2bfloat16(v.w)};
  *reinterpret_cast<uint2*>(dst + i) = *reinterpret_cast<const uint2*>(h);
}

// ===================== gemm_qkv (256x256, 8-phase core) =====================
// grid: 384 blocks = mt(32) x nt(12), XCD-swizzled (384 % 8 == 0).
__launch_bounds__(512, 2)
__global__ void gemm_qkv(const __hip_bfloat16* __restrict__ xb,
                         const __hip_bfloat16* __restrict__ Wb,
                         __hip_bfloat16* __restrict__ Q,
                         __hip_bfloat16* __restrict__ Kb,
                         __hip_bfloat16* __restrict__ Vt) {
  __shared__ __hip_bfloat16 lds[2 * BUFE];
  int id = blockIdx.x;
  int swz = (id & 7) * 48 + (id >> 3);
  int mt = swz / 12, nt = swz % 12;
  int tid = threadIdx.x, lane = tid & 63, lr = lane & 15, lg = lane >> 4;
  int w = tid >> 6, wm = w >> 2, wn = w & 3;
  f32x4 acc[8][4];
  f32x4 zero = {0.f, 0.f, 0.f, 0.f};
#pragma unroll
  for (int i = 0; i < 8; i++)
#pragma unroll
    for (int j = 0; j < 4; j++) acc[i][j] = zero;

  gemm8ph(xb + (size_t)mt * 256 * 1024, 1024,
          Wb + (size_t)nt * 256 * 1024, 1024, 16, lds, tid, acc);

  int which = nt >> 2;                   // 0=Q, 1=K, 2=V
  int ncol0 = (nt & 3) * 256 + wn * 64;  // col within the 1024-wide output
  int mrow0 = mt * 256 + wm * 128;
#pragma unroll
  for (int mi = 0; mi < 8; mi++)
#pragma unroll
    for (int ni = 0; ni < 4; ni++)
#pragma unroll
      for (int r = 0; r < 4; r++) {
        int row = mrow0 + mi * 16 + lg * 4 + r;
        int col = ncol0 + ni * 16 + lr;
        __hip_bfloat16 hv = __float2bfloat16(acc[mi][ni][r]);
        if (which == 0)      Q[(size_t)row * 1024 + col] = hv;
        else if (which == 1) Kb[(size_t)row * 1024 + col] = hv;
        else {
          int b = row >> 11, s = row & 2047;
          Vt[((size_t)b * 1024 + col) * 2048 + s] = hv;
        }
      }
}

// ==================== qk_scores (256x128, r9 pipelined core) ================
__launch_bounds__(256, 2)
__global__ void qk_scores(const __hip_bfloat16* __restrict__ Q,
                          const __hip_bfloat16* __restrict__ Kb,
                          __hip_bfloat16* __restrict__ P,
                          float* __restrict__ Lpart) {
  int kt = blockIdx.x, qt = blockIdx.y, b = blockIdx.z;
  if (kt > 2 * qt + 1) return;
  __shared__ __hip_bfloat16 lds[3 * BUF3];
  int tid = threadIdx.x, lane = tid & 63, lr = lane & 15, lg = lane >> 4;
  int w = tid >> 6, wm = w >> 1, wn = w & 1;
  f32x4 acc[8][4];
  f32x4 zero = {0.f, 0.f, 0.f, 0.f};
#pragma unroll
  for (int i = 0; i < 8; i++)
#pragma unroll
    for (int j = 0; j < 4; j++) acc[i][j] = zero;

  gemm_core3p(Q + ((size_t)b * 2048 + qt * 256) * 1024, 1024,
              Kb + ((size_t)b * 2048 + kt * 128) * 1024, 1024, 32, lds, tid, acc);

  const float scale = 0.03125f;  // 1/sqrt(1024)
  float part[8][4];
#pragma unroll
  for (int i = 0; i < 8; i++)
#pragma unroll
    for (int r = 0; r < 4; r++) part[i][r] = 0.f;

  __hip_bfloat16* Pb = P + (size_t)b * 2048 * 2048;
#pragma unroll
  for (int mi = 0; mi < 8; mi++)
#pragma unroll
    for (int ni = 0; ni < 4; ni++)
#pragma unroll
      for (int r = 0; r < 4; r++) {
        int q = qt * 256 + wm * 128 + mi * 16 + lg * 4 + r;
        int k = kt * 128 + wn * 64 + ni * 16 + lr;
        float p = (k <= q) ? __expf(acc[mi][ni][r] * scale) : 0.f;
        __hip_bfloat16 hv = __float2bfloat16(p);
        Pb[(size_t)q * 2048 + k] = hv;
        part[mi][r] += __bfloat162float(hv);
      }

#pragma unroll
  for (int mi = 0; mi < 8; mi++)
#pragma unroll
    for (int r = 0; r < 4; r++) {
      float s = part[mi][r];
      s += __shfl_xor(s, 1); s += __shfl_xor(s, 2);
      s += __shfl_xor(s, 4); s += __shfl_xor(s, 8);
      part[mi][r] = s;
    }
  if (lr < 4) {
#pragma unroll
    for (int mi = 0; mi < 8; mi++) {
      int q = qt * 256 + wm * 128 + mi * 16 + lg * 4 + lr;
      Lpart[(((size_t)b * 16 + kt) * 2 + wn) * 2048 + q] = part[mi][lr];
    }
  }
}

__global__ void reduce_L(const float* __restrict__ Lpart, float* __restrict__ L) {
  int i = blockIdx.x * 256 + threadIdx.x;  // [0, 8192)
  int b = i >> 11, q = i & 2047;
  int nkt = (q >> 7) + 1;
  float s = 0.f;
  for (int kt = 0; kt < nkt; kt++) {
    s += Lpart[(((size_t)b * 16 + kt) * 2 + 0) * 2048 + q];
    s += Lpart[(((size_t)b * 16 + kt) * 2 + 1) * 2048 + q];
  }
  L[i] = s;
}

// ===================== pv_out (256x128, r9 pipelined core) ==================
__launch_bounds__(256, 2)
__global__ void pv_out(const __hip_bfloat16* __restrict__ P,
                       const __hip_bfloat16* __restrict__ Vt,
                       const float* __restrict__ L,
                       float* __restrict__ out) {
  int dt = blockIdx.x, qt = blockIdx.y, b = blockIdx.z;
  __shared__ __hip_bfloat16 lds[3 * BUF3];
  int tid = threadIdx.x, lane = tid & 63, lr = lane & 15, lg = lane >> 4;
  int w = tid >> 6, wm = w >> 1, wn = w & 1;
  f32x4 acc[8][4];
  f32x4 zero = {0.f, 0.f, 0.f, 0.f};
#pragma unroll
  for (int i = 0; i < 8; i++)
#pragma unroll
    for (int j = 0; j < 4; j++) acc[i][j] = zero;

  gemm_core3p(P + (size_t)b * 2048 * 2048 + (size_t)qt * 256 * 2048, 2048,
              Vt + (size_t)b * 1024 * 2048 + (size_t)dt * 128 * 2048, 2048,
              (qt + 1) * 8, lds, tid, acc);

#pragma unroll
  for (int mi = 0; mi < 8; mi++)
#pragma unroll
    for (int r = 0; r < 4; r++) {
      int q = qt * 256 + wm * 128 + mi * 16 + lg * 4 + r;  // batch-local row
      float inv = 1.f / L[(size_t)b * 2048 + q];
#pragma unroll
      for (int ni = 0; ni < 4; ni++) {
        int d = dt * 128 + wn * 64 + ni * 16 + lr;
        out[((size_t)b * 2048 + q) * 1024 + d] = acc[mi][ni][r] * inv;
      }
    }
}

extern "C" void kernel_launch(void* const* d_in, const int* in_sizes, int n_in,
                              void* d_out, int out_size, void* d_ws, size_t ws_size,
                              hipStream_t stream) {
  const float* x  = (const float*)d_in[0];
  const float* Wq = (const float*)d_in[1];
  const float* Wk = (const float*)d_in[2];
  const float* Wv = (const float*)d_in[3];
  float* out = (float*)d_out;
  char* ws = (char*)d_ws;
  if (ws_size < WS_NEED) return;

  __hip_bfloat16* xb = (__hip_bfloat16*)(ws + OFF_XB);
  __hip_bfloat16* Wb = (__hip_bfloat16*)(ws + OFF_WB);
  __hip_bfloat16* Q  = (__hip_bfloat16*)(ws + OFF_Q);
  __hip_bfloat16* Kb = (__hip_bfloat16*)(ws + OFF_K);
  __hip_bfloat16* Vt = (__hip_bfloat16*)(ws + OFF_VT);
  __hip_bfloat16* P  = (__hip_bfloat16*)(ws + OFF_P);
  float* Lpart = (float*)(ws + OFF_LP);
  float* L     = (float*)(ws + OFF_L);

  cast_f32_bf16<<<8192, 256, 0, stream>>>(x, xb, MTOK * DD);
  cast_w3<<<3072, 256, 0, stream>>>(Wq, Wk, Wv, Wb);

  gemm_qkv<<<384, 512, 0, stream>>>(xb, Wb, Q, Kb, Vt);
  qk_scores<<<dim3(16, 8, 4), 256, 0, stream>>>(Q, Kb, P, Lpart);
  reduce_L<<<32, 256, 0, stream>>>(Lpart, L);
  pv_out<<<dim3(8, 8, 4), 256, 0, stream>>>(P, Vt, L, out);
}